// Round 1
// baseline (713.206 us; speedup 1.0000x reference)
//
#include <hip/hip_runtime.h>
#include <hip/hip_fp16.h>
#include <math.h>

#define N_NODES 100000
#define N_EDGES 3200000
#define D_IN    128
#define H1      16

#define BSH     8
#define NPB     256                    // nodes per bucket
#define NB      391                    // ceil(100000/256)
#define CAP     13056                  // eop region capacity (x16; padded fill ~12280 +5.7sigma)
#define PBLK    512
#define CHUNK   6250                   // N_EDGES / PBLK exact
#define ELS_CAP 12128                  // >= 6250 + 391*15 = 12115, multiple of 16
#define NLINES  (ELS_CAP / 16)         // 758
#define MROWS   64

// eop: NB regions of CAP uints (region base 64B-aligned).
// After k_partition: packed (src<<8 | dloc) runs, run per (block,bucket) padded
// to 16-edge (64B) multiples with 0xFFFFFFFF sentinels; the block locally
// bucket-sorts its chunk in LDS and writes it out COALESCED so every 64B line
// is produced by one full-line write burst (no partial-line L2 evictions).
// NOTE: no compaction pass anymore — k_deg counts degrees from the padded runs,
// and the agg kernels stream the padded runs directly into per-bucket LDS
// accumulators (ds_add_f32), skipping the CSR build entirely.

__global__ __launch_bounds__(512) void k_zero(int* __restrict__ cursor) {
    int t = threadIdx.x;
    if (t < NB) cursor[t] = 0;
}

// ---- partition: rank -> scan -> LDS bucket-sort -> coalesced full-line writeout ----
__global__ __launch_bounds__(512) void k_partition(const int* __restrict__ ei,
                                                   int* __restrict__ cursor,
                                                   unsigned int* __restrict__ eop) {
    __shared__ int h[512];                       // per-bucket counts (pad to 512)
    __shared__ int loff[512];                    // scan array -> exclusive local offsets
    __shared__ int resv[NB];                     // global region offsets
    __shared__ unsigned short owner[NLINES];     // line -> bucket
    __shared__ unsigned char rank8[CHUNK];       // per-edge rank in its run (<255)
    __shared__ unsigned int els[ELS_CAP];        // 48.5 KB staging
    int t = threadIdx.x;
    h[t] = 0;
    __syncthreads();
    int c0 = blockIdx.x * CHUNK;
    const int* srcs = ei + c0;
    const int* dsts = ei + N_EDGES + c0;
    for (int i = t; i < CHUNK; i += 512)
        rank8[i] = (unsigned char)atomicAdd(&h[dsts[i] >> BSH], 1);
    __syncthreads();
    int cp = (h[t] + 15) & ~15;                  // run padded to 64B multiple
    loff[t] = cp;
    __syncthreads();
    for (int o = 1; o < 512; o <<= 1) {          // inclusive Hillis-Steele
        int u = (t >= o) ? loff[t - o] : 0;
        __syncthreads();
        loff[t] += u;
        __syncthreads();
    }
    int inc = loff[t];
    int totalpad = loff[511];                    // <= ELS_CAP by construction
    int ex = inc - cp;
    __syncthreads();
    loff[t] = ex;                                // now exclusive
    if (t < NB && cp) {
        resv[t] = atomicAdd(&cursor[t], cp);     // stays 16-aligned
        int l0 = ex >> 4;
        for (int k = 0; k < (cp >> 4); ++k) owner[l0 + k] = (unsigned short)t;
    }
    for (int i = t; i < totalpad; i += 512) els[i] = 0xFFFFFFFFu;   // sentinels
    __syncthreads();
    for (int i = t; i < CHUNK; i += 512) {       // LDS bucket-sort scatter
        int s = srcs[i];
        int d = dsts[i];
        int b = d >> BSH;
        els[loff[b] + (int)rank8[i]] = ((unsigned)s << BSH) | (unsigned)(d & (NPB - 1));
    }
    __syncthreads();
    for (int i = t; i < totalpad; i += 512) {    // coalesced: full 64B lines
        int b   = owner[i >> 4];
        int pos = resv[b] + (i - loff[b]);
        if (pos < CAP)                           // statistically impossible guard
            eop[(size_t)b * CAP + pos] = els[i];
    }
}

// ---- degree count: slim read-only pass over padded runs -> dinv ----
__global__ __launch_bounds__(512) void k_deg(const int* __restrict__ cursor,
                                             const unsigned int* __restrict__ eop,
                                             float* __restrict__ dinv) {
    __shared__ int cnt[NPB];
    int t = threadIdx.x, b = blockIdx.x;
    if (t < NPB) cnt[t] = 0;
    __syncthreads();
    int n = cursor[b]; if (n > CAP) n = CAP;
    const unsigned int* reg = eop + (size_t)b * CAP;
    for (int i = t; i < n; i += 512) {
        unsigned int v = reg[i];
        if ((int)v >= 0) atomicAdd(&cnt[v & (NPB - 1)], 1);   // real entry
    }
    __syncthreads();
    if (t < NPB) {
        int node = (b << BSH) + t;
        if (node < N_NODES)
            dinv[node] = rsqrtf((float)(cnt[t] + 1));         // +1 self-loop
    }
}

// ---- matmul: wave = 64 rows x 4 cols, x in LDS (pad 129), W uniform loads ----
__global__ __launch_bounds__(256) void k_mm1(const float* __restrict__ x,
                                             const float* __restrict__ W1,
                                             const float* __restrict__ dinv,
                                             __half* __restrict__ h1h) {
    __shared__ float sX[MROWS][D_IN + 1];   // 33 KB
    int t = threadIdx.x;
    int r0 = blockIdx.x * MROWS;
    for (int i = t; i < MROWS * (D_IN / 4); i += 256) {
        int row = i >> 5, c4 = i & 31;
        int grow = r0 + row;
        float4 v = (grow < N_NODES) ? ((const float4*)x)[(size_t)grow * 32 + c4]
                                    : make_float4(0.f, 0.f, 0.f, 0.f);
        sX[row][c4 * 4 + 0] = v.x; sX[row][c4 * 4 + 1] = v.y;
        sX[row][c4 * 4 + 2] = v.z; sX[row][c4 * 4 + 3] = v.w;
    }
    __syncthreads();
    int lane = t & 63;
    int c0 = __builtin_amdgcn_readfirstlane((t >> 6) * 4);
    float a0 = 0.f, a1 = 0.f, a2 = 0.f, a3 = 0.f;
#pragma unroll 4
    for (int d = 0; d < D_IN; ++d) {
        float xv = sX[lane][d];
        a0 = fmaf(xv, W1[d * 16 + c0 + 0], a0);
        a1 = fmaf(xv, W1[d * 16 + c0 + 1], a1);
        a2 = fmaf(xv, W1[d * 16 + c0 + 2], a2);
        a3 = fmaf(xv, W1[d * 16 + c0 + 3], a3);
    }
    int grow = r0 + lane;
    if (grow < N_NODES) {
        float di = dinv[grow];
        __half2* o = (__half2*)(h1h + (size_t)grow * H1 + c0);
        o[0] = __floats2half2_rn(a0 * di, a1 * di);
        o[1] = __floats2half2_rn(a2 * di, a3 * di);
    }
}

// ---- layer-1 agg: stream padded run, 16 lanes/edge, LDS float-atomic acc,
//      then fused self-loop + relu + W2 per node ----
__global__ __launch_bounds__(512) void k_agg1(const int* __restrict__ cursor,
                                              const unsigned int* __restrict__ eop,
                                              const __half* __restrict__ h1h,
                                              const float* __restrict__ dinv,
                                              const float* __restrict__ b1,
                                              const float* __restrict__ W2,
                                              float2* __restrict__ h2f) {
    __shared__ float acc[NPB * H1];              // 16 KB
    int t = threadIdx.x, b = blockIdx.x;
    for (int i = t; i < NPB * H1; i += 512) acc[i] = 0.f;
    __syncthreads();
    int n = cursor[b]; if (n > CAP) n = CAP;
    const unsigned int* reg = eop + (size_t)b * CAP;
    int g = t >> 4, l = t & 15;                  // 32 groups x 16 lanes
    int nmain = n & ~127;
    int i0 = 0;
    for (; i0 < nmain; i0 += 128) {              // unroll 4: keep 4 gathers in flight
        int idx = i0 + g;
        unsigned int v0 = reg[idx      ];
        unsigned int v1 = reg[idx +  32];
        unsigned int v2 = reg[idx +  64];
        unsigned int v3 = reg[idx +  96];
        unsigned s0 = ((int)v0 >= 0) ? (v0 >> BSH) : 0u;
        unsigned s1 = ((int)v1 >= 0) ? (v1 >> BSH) : 0u;
        unsigned s2 = ((int)v2 >= 0) ? (v2 >> BSH) : 0u;
        unsigned s3 = ((int)v3 >= 0) ? (v3 >> BSH) : 0u;
        float f0 = __half2float(h1h[s0 * H1 + l]);
        float f1 = __half2float(h1h[s1 * H1 + l]);
        float f2 = __half2float(h1h[s2 * H1 + l]);
        float f3 = __half2float(h1h[s3 * H1 + l]);
        atomicAdd(&acc[(v0 & (NPB - 1)) * H1 + l], ((int)v0 >= 0) ? f0 : 0.f);
        atomicAdd(&acc[(v1 & (NPB - 1)) * H1 + l], ((int)v1 >= 0) ? f1 : 0.f);
        atomicAdd(&acc[(v2 & (NPB - 1)) * H1 + l], ((int)v2 >= 0) ? f2 : 0.f);
        atomicAdd(&acc[(v3 & (NPB - 1)) * H1 + l], ((int)v3 >= 0) ? f3 : 0.f);
    }
    for (int i = nmain + g; i < n; i += 32) {    // tail
        unsigned int v = reg[i];
        unsigned s = ((int)v >= 0) ? (v >> BSH) : 0u;
        float f = __half2float(h1h[s * H1 + l]);
        atomicAdd(&acc[(v & (NPB - 1)) * H1 + l], ((int)v >= 0) ? f : 0.f);
    }
    __syncthreads();
    for (int p = 0; p < NPB / 32; ++p) {         // finalize 32 nodes/pass
        int nl = p * 32 + g;
        int node = (b << BSH) + nl;
        if (node < N_NODES) {
            float s = acc[nl * H1 + l] + __half2float(h1h[(size_t)node * H1 + l]);
            float di = dinv[node];
            float h = fmaxf(fmaf(di, s, b1[l]), 0.f);
            float p0 = h * W2[2 * l], p1 = h * W2[2 * l + 1];
#pragma unroll
            for (int off = 1; off < 16; off <<= 1) {
                p0 += __shfl_xor(p0, off);
                p1 += __shfl_xor(p1, off);
            }
            if (l == 0) h2f[node] = make_float2(p0 * di, p1 * di);
        }
    }
}

// ---- layer-2 agg: stream padded run, 1 lane/edge, LDS float-atomic acc,
//      then b2 + log_softmax ----
__global__ __launch_bounds__(512) void k_agg2(const int* __restrict__ cursor,
                                              const unsigned int* __restrict__ eop,
                                              const float2* __restrict__ h2f,
                                              const float* __restrict__ dinv,
                                              const float* __restrict__ b2,
                                              float* __restrict__ out) {
    __shared__ float accx[NPB];
    __shared__ float accy[NPB];
    int t = threadIdx.x, b = blockIdx.x;
    if (t < NPB) { accx[t] = 0.f; accy[t] = 0.f; }
    __syncthreads();
    int n = cursor[b]; if (n > CAP) n = CAP;
    const unsigned int* reg = eop + (size_t)b * CAP;
    int nmain = n & ~2047;
    int i0 = 0;
    for (; i0 < nmain; i0 += 2048) {             // unroll 4: 4 gathers in flight
        int idx = i0 + t;
        unsigned int v0 = reg[idx       ];
        unsigned int v1 = reg[idx +  512];
        unsigned int v2 = reg[idx + 1024];
        unsigned int v3 = reg[idx + 1536];
        unsigned s0 = ((int)v0 >= 0) ? (v0 >> BSH) : 0u;
        unsigned s1 = ((int)v1 >= 0) ? (v1 >> BSH) : 0u;
        unsigned s2 = ((int)v2 >= 0) ? (v2 >> BSH) : 0u;
        unsigned s3 = ((int)v3 >= 0) ? (v3 >> BSH) : 0u;
        float2 m0 = h2f[s0];
        float2 m1 = h2f[s1];
        float2 m2 = h2f[s2];
        float2 m3 = h2f[s3];
        atomicAdd(&accx[v0 & (NPB - 1)], ((int)v0 >= 0) ? m0.x : 0.f);
        atomicAdd(&accy[v0 & (NPB - 1)], ((int)v0 >= 0) ? m0.y : 0.f);
        atomicAdd(&accx[v1 & (NPB - 1)], ((int)v1 >= 0) ? m1.x : 0.f);
        atomicAdd(&accy[v1 & (NPB - 1)], ((int)v1 >= 0) ? m1.y : 0.f);
        atomicAdd(&accx[v2 & (NPB - 1)], ((int)v2 >= 0) ? m2.x : 0.f);
        atomicAdd(&accy[v2 & (NPB - 1)], ((int)v2 >= 0) ? m2.y : 0.f);
        atomicAdd(&accx[v3 & (NPB - 1)], ((int)v3 >= 0) ? m3.x : 0.f);
        atomicAdd(&accy[v3 & (NPB - 1)], ((int)v3 >= 0) ? m3.y : 0.f);
    }
    for (int i = nmain + t; i < n; i += 512) {   // tail
        unsigned int v = reg[i];
        unsigned s = ((int)v >= 0) ? (v >> BSH) : 0u;
        float2 m = h2f[s];
        atomicAdd(&accx[v & (NPB - 1)], ((int)v >= 0) ? m.x : 0.f);
        atomicAdd(&accy[v & (NPB - 1)], ((int)v >= 0) ? m.y : 0.f);
    }
    __syncthreads();
    if (t < NPB) {
        int node = (b << BSH) + t;
        if (node < N_NODES) {
            float di = dinv[node];
            float2 self = h2f[node];
            float a0 = fmaf(di, accx[t] + self.x, b2[0]);
            float a1 = fmaf(di, accy[t] + self.y, b2[1]);
            float m  = fmaxf(a0, a1);
            float lg = logf(expf(a0 - m) + expf(a1 - m));
            out[2 * node]     = a0 - m - lg;
            out[2 * node + 1] = a1 - m - lg;
        }
    }
}

extern "C" void kernel_launch(void* const* d_in, const int* in_sizes, int n_in,
                              void* d_out, int out_size, void* d_ws, size_t ws_size,
                              hipStream_t stream) {
    const float* x  = (const float*)d_in[0];
    const int*   ei = (const int*)d_in[1];
    const float* W1 = (const float*)d_in[2];
    const float* b1 = (const float*)d_in[3];
    const float* W2 = (const float*)d_in[4];
    const float* b2 = (const float*)d_in[5];
    float* out = (float*)d_out;

    // workspace carve (~23.7 MB); eop base offset 4417536 B = 64B-aligned
    int*          cursor = (int*)d_ws;                       // 512
    float*        dinv   = (float*)(cursor + 512);           // N (pad 100352)
    __half*       h1h    = (__half*)(dinv + 100352);         // N*16 halves, 3.2 MB
    float2*       h2f    = (float2*)(h1h + (size_t)100352 * H1);  // N float2
    unsigned int* eop    = (unsigned int*)(h2f + 100352);    // NB*CAP = 20.4 MB

    k_zero     <<<1,    512, 0, stream>>>(cursor);
    k_partition<<<PBLK, 512, 0, stream>>>(ei, cursor, eop);
    k_deg      <<<NB,   512, 0, stream>>>(cursor, eop, dinv);
    k_mm1      <<<(N_NODES + MROWS - 1) / MROWS, 256, 0, stream>>>(x, W1, dinv, h1h);
    k_agg1     <<<NB,   512, 0, stream>>>(cursor, eop, h1h, dinv, b1, W2, h2f);
    k_agg2     <<<NB,   512, 0, stream>>>(cursor, eop, h2f, dinv, b2, out);
}

// Round 2
// 221.574 us; speedup vs baseline: 3.2188x; 3.2188x over previous
//
#include <hip/hip_runtime.h>
#include <hip/hip_fp16.h>
#include <math.h>

#define N_NODES 100000
#define N_EDGES 3200000
#define D_IN    128
#define H1      16

#define BSH     8
#define NPB     256                    // nodes per bucket
#define NB      391                    // ceil(100000/256)
#define CAP     13056                  // eop region capacity (x16; padded fill ~12280 +5.7sigma)
#define PBLK    512
#define CHUNK   6250                   // N_EDGES / PBLK exact
#define ELS_CAP 12128                  // >= 6250 + 391*15 = 12115, multiple of 16
#define NLINES  (ELS_CAP / 16)         // 758
#define MROWS   64

// eop: NB regions of CAP uints (region base 64B-aligned).
// After k_partition: packed (src<<8 | dloc) runs, run per (block,bucket) padded
// to 16-edge (64B) multiples with 0xFFFFFFFF sentinels; the block locally
// bucket-sorts its chunk in LDS and writes it out COALESCED so every 64B line
// is produced by one full-line write burst (no partial-line L2 evictions).
// After k_build: plain src, grouped (CSR) by dst node, compact at region front.
// k_build does ONE LDS-atomic pass: the count pass's returned rank is stashed
// in bits 25..31 of the staged entry (src occupies 8..24, rank<=127), so the
// compaction pass is atomic-free. Sentinels are detected via src-field >= N.

// ---- partition: rank -> scan -> LDS bucket-sort -> coalesced full-line writeout ----
__global__ __launch_bounds__(512) void k_partition(const int* __restrict__ ei,
                                                   int* __restrict__ cursor,
                                                   unsigned int* __restrict__ eop) {
    __shared__ int h[512];                       // per-bucket counts (pad to 512)
    __shared__ int loff[512];                    // scan array -> exclusive local offsets
    __shared__ int resv[NB];                     // global region offsets
    __shared__ unsigned short owner[NLINES];     // line -> bucket
    __shared__ unsigned char rank8[CHUNK];       // per-edge rank in its run (<255)
    __shared__ unsigned int els[ELS_CAP];        // 48.5 KB staging
    int t = threadIdx.x;
    h[t] = 0;
    __syncthreads();
    int c0 = blockIdx.x * CHUNK;
    const int* srcs = ei + c0;
    const int* dsts = ei + N_EDGES + c0;
    for (int i = t; i < CHUNK; i += 512)
        rank8[i] = (unsigned char)atomicAdd(&h[dsts[i] >> BSH], 1);
    __syncthreads();
    int cp = (h[t] + 15) & ~15;                  // run padded to 64B multiple
    loff[t] = cp;
    __syncthreads();
    for (int o = 1; o < 512; o <<= 1) {          // inclusive Hillis-Steele
        int u = (t >= o) ? loff[t - o] : 0;
        __syncthreads();
        loff[t] += u;
        __syncthreads();
    }
    int inc = loff[t];
    int totalpad = loff[511];                    // <= ELS_CAP by construction
    int ex = inc - cp;
    __syncthreads();
    loff[t] = ex;                                // now exclusive
    if (t < NB && cp) {
        resv[t] = atomicAdd(&cursor[t], cp);     // stays 16-aligned
        int l0 = ex >> 4;
        for (int k = 0; k < (cp >> 4); ++k) owner[l0 + k] = (unsigned short)t;
    }
    for (int i = t; i < totalpad; i += 512) els[i] = 0xFFFFFFFFu;   // sentinels
    __syncthreads();
    for (int i = t; i < CHUNK; i += 512) {       // LDS bucket-sort scatter
        int s = srcs[i];
        int d = dsts[i];
        int b = d >> BSH;
        els[loff[b] + (int)rank8[i]] = ((unsigned)s << BSH) | (unsigned)(d & (NPB - 1));
    }
    __syncthreads();
    for (int i = t; i < totalpad; i += 512) {    // coalesced: full 64B lines
        int b   = owner[i >> 4];
        int pos = resv[b] + (i - loff[b]);
        if (pos < CAP)                           // statistically impossible guard
            eop[(size_t)b * CAP + pos] = els[i];
    }
}

// ---- build: uint4 stage, single count+rank atomic pass, atomic-free compaction ----
__global__ __launch_bounds__(512) void k_build(const int* __restrict__ cursor,
                                               unsigned int* __restrict__ eop,
                                               int* __restrict__ nstart,
                                               int* __restrict__ ndeg,
                                               float* __restrict__ dinv) {
    __shared__ unsigned int els[CAP];   // 52.2 KB
    __shared__ int cnt[NPB];
    __shared__ int off[NPB];
    int t = threadIdx.x, b = blockIdx.x;
    if (t < NPB) cnt[t] = 0;
    __syncthreads();
    int n = cursor[b]; if (n > CAP) n = CAP;     // padded fill; multiple of 16
    unsigned int* reg = eop + (size_t)b * CAP;
    for (int i4 = t; i4 < (n >> 2); i4 += 512) { // stage + count + rank, one pass
        uint4 w = ((const uint4*)reg)[i4];
        unsigned int e0 = w.x, e1 = w.y, e2 = w.z, e3 = w.w;
        int r;
        if ((int)e0 >= 0) { r = atomicAdd(&cnt[e0 & (NPB - 1)], 1); e0 |= (unsigned)r << 25; }
        if ((int)e1 >= 0) { r = atomicAdd(&cnt[e1 & (NPB - 1)], 1); e1 |= (unsigned)r << 25; }
        if ((int)e2 >= 0) { r = atomicAdd(&cnt[e2 & (NPB - 1)], 1); e2 |= (unsigned)r << 25; }
        if ((int)e3 >= 0) { r = atomicAdd(&cnt[e3 & (NPB - 1)], 1); e3 |= (unsigned)r << 25; }
        ((uint4*)els)[i4] = make_uint4(e0, e1, e2, e3);
    }
    __syncthreads();
    int val = (t < NPB) ? cnt[t] : 0;
    if (t < NPB) off[t] = val;
    __syncthreads();
    for (int o = 1; o < NPB; o <<= 1) {          // inclusive Hillis-Steele
        int u = 0;
        if (t < NPB && t >= o) u = off[t - o];
        __syncthreads();
        if (t < NPB) off[t] += u;
        __syncthreads();
    }
    if (t < NPB) {
        int ex = off[t] - val;                   // exclusive
        off[t] = ex;
        int node = (b << BSH) + t;
        if (node < N_NODES) {
            nstart[node] = b * CAP + ex;
            ndeg[node]   = val;
            dinv[node]   = rsqrtf((float)(val + 1));   // +1 self-loop
        }
    }
    __syncthreads();
    for (int i4 = t; i4 < (n >> 2); i4 += 512) { // rank-addressed compact CSR
        uint4 w = ((const uint4*)els)[i4];
        unsigned int e; unsigned s;
        e = w.x; s = (e >> 8) & 0x1FFFFu;
        if (s < N_NODES) reg[off[e & (NPB - 1)] + (int)(e >> 25)] = s;
        e = w.y; s = (e >> 8) & 0x1FFFFu;
        if (s < N_NODES) reg[off[e & (NPB - 1)] + (int)(e >> 25)] = s;
        e = w.z; s = (e >> 8) & 0x1FFFFu;
        if (s < N_NODES) reg[off[e & (NPB - 1)] + (int)(e >> 25)] = s;
        e = w.w; s = (e >> 8) & 0x1FFFFu;
        if (s < N_NODES) reg[off[e & (NPB - 1)] + (int)(e >> 25)] = s;
    }
}

// ---- matmul: wave = 64 rows x 4 cols, x in LDS (pad 129), W uniform loads ----
__global__ __launch_bounds__(256) void k_mm1(const float* __restrict__ x,
                                             const float* __restrict__ W1,
                                             const float* __restrict__ dinv,
                                             __half* __restrict__ h1h) {
    __shared__ float sX[MROWS][D_IN + 1];   // 33 KB
    int t = threadIdx.x;
    int r0 = blockIdx.x * MROWS;
    for (int i = t; i < MROWS * (D_IN / 4); i += 256) {
        int row = i >> 5, c4 = i & 31;
        int grow = r0 + row;
        float4 v = (grow < N_NODES) ? ((const float4*)x)[(size_t)grow * 32 + c4]
                                    : make_float4(0.f, 0.f, 0.f, 0.f);
        sX[row][c4 * 4 + 0] = v.x; sX[row][c4 * 4 + 1] = v.y;
        sX[row][c4 * 4 + 2] = v.z; sX[row][c4 * 4 + 3] = v.w;
    }
    __syncthreads();
    int lane = t & 63;
    int c0 = __builtin_amdgcn_readfirstlane((t >> 6) * 4);
    float a0 = 0.f, a1 = 0.f, a2 = 0.f, a3 = 0.f;
#pragma unroll 4
    for (int d = 0; d < D_IN; ++d) {
        float xv = sX[lane][d];
        a0 = fmaf(xv, W1[d * 16 + c0 + 0], a0);
        a1 = fmaf(xv, W1[d * 16 + c0 + 1], a1);
        a2 = fmaf(xv, W1[d * 16 + c0 + 2], a2);
        a3 = fmaf(xv, W1[d * 16 + c0 + 3], a3);
    }
    int grow = r0 + lane;
    if (grow < N_NODES) {
        float di = dinv[grow];
        __half2* o = (__half2*)(h1h + (size_t)grow * H1 + c0);
        o[0] = __floats2half2_rn(a0 * di, a1 * di);
        o[1] = __floats2half2_rn(a2 * di, a3 * di);
    }
}

// ---- layer-1 agg: 16 lanes/node, register accumulate, fused relu+W2 ----
__global__ __launch_bounds__(256) void k_agg1(const unsigned int* __restrict__ eop,
                                              const int* __restrict__ nstart,
                                              const int* __restrict__ ndeg,
                                              const __half* __restrict__ h1h,
                                              const float* __restrict__ dinv,
                                              const float* __restrict__ b1,
                                              const float* __restrict__ W2,
                                              float2* __restrict__ h2f) {
    int t = threadIdx.x;
    int g = t >> 4, l = t & 15;
    int node = blockIdx.x * 16 + g;          // 6250*16 == N exactly
    int e0 = nstart[node], e1 = e0 + ndeg[node];
    float acc = 0.f;
    int j = e0;
    for (; j + 4 <= e1; j += 4) {
        int s0 = eop[j], s1 = eop[j + 1], s2 = eop[j + 2], s3 = eop[j + 3];
        acc += __half2float(h1h[s0 * H1 + l]) + __half2float(h1h[s1 * H1 + l])
             + __half2float(h1h[s2 * H1 + l]) + __half2float(h1h[s3 * H1 + l]);
    }
    for (; j < e1; ++j) acc += __half2float(h1h[(int)eop[j] * H1 + l]);
    float di = dinv[node];
    float s  = acc + __half2float(h1h[node * H1 + l]);   // + self-loop
    float h  = fmaxf(fmaf(di, s, b1[l]), 0.f);
    float p0 = h * W2[2 * l], p1 = h * W2[2 * l + 1];
#pragma unroll
    for (int off = 1; off < 16; off <<= 1) {
        p0 += __shfl_xor(p0, off);
        p1 += __shfl_xor(p1, off);
    }
    if (l == 0) h2f[node] = make_float2(p0 * di, p1 * di);
}

// ---- layer-2 agg: 4 lanes/node + b2 + log_softmax ----
__global__ __launch_bounds__(256) void k_agg2(const unsigned int* __restrict__ eop,
                                              const int* __restrict__ nstart,
                                              const int* __restrict__ ndeg,
                                              const float2* __restrict__ h2f,
                                              const float* __restrict__ dinv,
                                              const float* __restrict__ b2,
                                              float* __restrict__ out) {
    int tg = blockIdx.x * 256 + threadIdx.x;
    int node = tg >> 2, l = tg & 3;
    if (node >= N_NODES) return;
    int e0 = nstart[node], e1 = e0 + ndeg[node];
    float ax = 0.f, ay = 0.f;
    for (int j = e0 + l; j < e1; j += 4) {
        float2 m = h2f[eop[j]];
        ax += m.x; ay += m.y;
    }
    ax += __shfl_xor(ax, 1); ay += __shfl_xor(ay, 1);
    ax += __shfl_xor(ax, 2); ay += __shfl_xor(ay, 2);
    if (l == 0) {
        float di = dinv[node];
        float2 self = h2f[node];
        float a0 = fmaf(di, ax + self.x, b2[0]);
        float a1 = fmaf(di, ay + self.y, b2[1]);
        float m  = fmaxf(a0, a1);
        float lg = logf(expf(a0 - m) + expf(a1 - m));
        out[2 * node]     = a0 - m - lg;
        out[2 * node + 1] = a1 - m - lg;
    }
}

extern "C" void kernel_launch(void* const* d_in, const int* in_sizes, int n_in,
                              void* d_out, int out_size, void* d_ws, size_t ws_size,
                              hipStream_t stream) {
    const float* x  = (const float*)d_in[0];
    const int*   ei = (const int*)d_in[1];
    const float* W1 = (const float*)d_in[2];
    const float* b1 = (const float*)d_in[3];
    const float* W2 = (const float*)d_in[4];
    const float* b2 = (const float*)d_in[5];
    float* out = (float*)d_out;

    // workspace carve (~25.6 MB); eop base offset 5220352 B = 64B-aligned
    int*          cursor = (int*)d_ws;                       // 512
    int*          nstart = cursor + 512;                     // N (pad 100352)
    int*          ndeg   = nstart + 100352;                  // N (pad 100352)
    float*        dinv   = (float*)(ndeg + 100352);          // N (pad 100352)
    __half*       h1h    = (__half*)(dinv + 100352);         // N*16 halves, 3.2 MB
    float2*       h2f    = (float2*)(h1h + (size_t)100352 * H1);  // N float2
    unsigned int* eop    = (unsigned int*)(h2f + 100352);    // NB*CAP = 20.4 MB

    hipMemsetAsync(cursor, 0, 512 * sizeof(int), stream);    // capture-safe
    k_partition<<<PBLK, 512, 0, stream>>>(ei, cursor, eop);
    k_build    <<<NB,   512, 0, stream>>>(cursor, eop, nstart, ndeg, dinv);
    k_mm1      <<<(N_NODES + MROWS - 1) / MROWS, 256, 0, stream>>>(x, W1, dinv, h1h);
    k_agg1     <<<N_NODES / 16, 256, 0, stream>>>(eop, nstart, ndeg, h1h, dinv, b1, W2, h2f);
    k_agg2     <<<(N_NODES * 4 + 255) / 256, 256, 0, stream>>>(eop, nstart, ndeg, h2f, dinv, b2, out);
}

// Round 3
// 206.434 us; speedup vs baseline: 3.4549x; 1.0733x over previous
//
#include <hip/hip_runtime.h>
#include <hip/hip_fp16.h>
#include <math.h>

#define N_NODES 100000
#define N_EDGES 3200000
#define D_IN    128
#define H1      16

#define BSH     8
#define NPB     256                    // nodes per bucket
#define NB      391                    // ceil(100000/256)
#define CAP     13056                  // eop region capacity (x16; padded fill ~12280 +5.7sigma)
#define PBLK    512
#define CHUNK   6250                   // N_EDGES / PBLK exact
#define ELS_CAP 12128                  // >= 6250 + 391*15 = 12115, multiple of 16
#define NLINES  (ELS_CAP / 16)         // 758
#define MROWS   64

// eop: NB regions of CAP uints (region base 64B-aligned).
// k_partition: packed (src<<8 | dloc) runs, run per (block,bucket) padded to
// 16-edge (64B) multiples with 0xFFFFFFFF sentinels; block bucket-sorts its
// chunk in LDS, writes coalesced full 64B lines.
// k_build: ONE LDS-atomic pass (rank stashed in bits 25..31), atomic-free
// compaction to plain src grouped (CSR) by dst node at region front.
// k_agg1: 8 lanes/node, lane-parallel eop loads + shfl broadcast, half2
// gathers -> 9 VMEM insts per 64 edges.

// ---- partition: rank -> wave-scan -> LDS bucket-sort -> coalesced writeout ----
__global__ __launch_bounds__(512) void k_partition(const int* __restrict__ ei,
                                                   int* __restrict__ cursor,
                                                   unsigned int* __restrict__ eop) {
    __shared__ int h[512];                       // per-bucket counts (pad to 512)
    __shared__ int loff[512];                    // exclusive local run offsets
    __shared__ int resv[NB];                     // global region offsets
    __shared__ int wsum[8], wpre[8];             // cross-wave scan
    __shared__ unsigned short owner[NLINES];     // line -> bucket
    __shared__ unsigned char rank8[CHUNK];       // per-edge rank in its run (<255)
    __shared__ unsigned int els[ELS_CAP];        // 48.5 KB staging
    int t = threadIdx.x;
    h[t] = 0;
    __syncthreads();
    int c0 = blockIdx.x * CHUNK;
    const int2* s2 = (const int2*)(ei + c0);
    const int2* d2 = (const int2*)(ei + N_EDGES + c0);
    for (int i = t; i < CHUNK / 2; i += 512) {   // int2 loads: count + rank
        int2 dd = d2[i];
        rank8[2 * i]     = (unsigned char)atomicAdd(&h[dd.x >> BSH], 1);
        rank8[2 * i + 1] = (unsigned char)atomicAdd(&h[dd.y >> BSH], 1);
    }
    __syncthreads();
    int cp = (h[t] + 15) & ~15;                  // run padded to 64B multiple
    int lane = t & 63, w = t >> 6;
    int v = cp;                                  // wave-level inclusive scan
#pragma unroll
    for (int o = 1; o < 64; o <<= 1) {
        int u = __shfl_up(v, o);
        if (lane >= o) v += u;
    }
    if (lane == 63) wsum[w] = v;
    __syncthreads();
    if (t < 8) {
        int s = wsum[t];
#pragma unroll
        for (int o = 1; o < 8; o <<= 1) {
            int u = __shfl_up(s, o);
            if (t >= o) s += u;
        }
        wpre[t] = s;                             // inclusive wave prefix
    }
    __syncthreads();
    int inc = v + ((w > 0) ? wpre[w - 1] : 0);   // inclusive over 512
    int totalpad = wpre[7];                      // <= ELS_CAP by construction
    int ex = inc - cp;                           // exclusive
    loff[t] = ex;
    if (t < NB && cp) {
        resv[t] = atomicAdd(&cursor[t], cp);     // stays 16-aligned
        int l0 = ex >> 4;
        for (int k = 0; k < (cp >> 4); ++k) owner[l0 + k] = (unsigned short)t;
    }
    for (int i = t; i < totalpad; i += 512) els[i] = 0xFFFFFFFFu;   // sentinels
    __syncthreads();
    for (int i = t; i < CHUNK / 2; i += 512) {   // LDS bucket-sort scatter
        int2 ss = s2[i];
        int2 dd = d2[i];                         // L2-hot re-read
        els[loff[dd.x >> BSH] + (int)rank8[2 * i]] =
            ((unsigned)ss.x << BSH) | (unsigned)(dd.x & (NPB - 1));
        els[loff[dd.y >> BSH] + (int)rank8[2 * i + 1]] =
            ((unsigned)ss.y << BSH) | (unsigned)(dd.y & (NPB - 1));
    }
    __syncthreads();
    for (int i = t; i < totalpad; i += 512) {    // coalesced: full 64B lines
        int b   = owner[i >> 4];
        int pos = resv[b] + (i - loff[b]);
        if (pos < CAP)                           // statistically impossible guard
            eop[(size_t)b * CAP + pos] = els[i];
    }
}

// ---- build: uint4 stage, single count+rank atomic pass, atomic-free compaction ----
__global__ __launch_bounds__(512) void k_build(const int* __restrict__ cursor,
                                               unsigned int* __restrict__ eop,
                                               int* __restrict__ nstart,
                                               int* __restrict__ ndeg,
                                               float* __restrict__ dinv) {
    __shared__ unsigned int els[CAP];   // 52.2 KB
    __shared__ int cnt[NPB];
    __shared__ int off[NPB];
    __shared__ int wsum[4], wpre[4];
    int t = threadIdx.x, b = blockIdx.x;
    if (t < NPB) cnt[t] = 0;
    __syncthreads();
    int n = cursor[b]; if (n > CAP) n = CAP;     // padded fill; multiple of 16
    unsigned int* reg = eop + (size_t)b * CAP;
    for (int i4 = t; i4 < (n >> 2); i4 += 512) { // stage + count + rank, one pass
        uint4 wv = ((const uint4*)reg)[i4];
        unsigned int e0 = wv.x, e1 = wv.y, e2 = wv.z, e3 = wv.w;
        int r;
        if ((int)e0 >= 0) { r = atomicAdd(&cnt[e0 & (NPB - 1)], 1); e0 |= (unsigned)r << 25; }
        if ((int)e1 >= 0) { r = atomicAdd(&cnt[e1 & (NPB - 1)], 1); e1 |= (unsigned)r << 25; }
        if ((int)e2 >= 0) { r = atomicAdd(&cnt[e2 & (NPB - 1)], 1); e2 |= (unsigned)r << 25; }
        if ((int)e3 >= 0) { r = atomicAdd(&cnt[e3 & (NPB - 1)], 1); e3 |= (unsigned)r << 25; }
        ((uint4*)els)[i4] = make_uint4(e0, e1, e2, e3);
    }
    __syncthreads();
    int val = (t < NPB) ? cnt[t] : 0;
    int lane = t & 63, w = t >> 6;
    int v = val;                                 // wave-level inclusive scan
#pragma unroll
    for (int o = 1; o < 64; o <<= 1) {
        int u = __shfl_up(v, o);
        if (lane >= o) v += u;
    }
    if (lane == 63 && w < 4) wsum[w] = v;
    __syncthreads();
    if (t < 4) {
        int s = wsum[t];
#pragma unroll
        for (int o = 1; o < 4; o <<= 1) {
            int u = __shfl_up(s, o);
            if (t >= o) s += u;
        }
        wpre[t] = s;
    }
    __syncthreads();
    if (t < NPB) {
        int inc = v + ((w > 0) ? wpre[w - 1] : 0);
        int ex = inc - val;                      // exclusive
        off[t] = ex;
        int node = (b << BSH) + t;
        if (node < N_NODES) {
            nstart[node] = b * CAP + ex;
            ndeg[node]   = val;
            dinv[node]   = rsqrtf((float)(val + 1));   // +1 self-loop
        }
    }
    __syncthreads();
    for (int i4 = t; i4 < (n >> 2); i4 += 512) { // rank-addressed compact CSR
        uint4 wv = ((const uint4*)els)[i4];
        unsigned int e; unsigned s;
        e = wv.x; s = (e >> 8) & 0x1FFFFu;
        if (s < N_NODES) reg[off[e & (NPB - 1)] + (int)(e >> 25)] = s;
        e = wv.y; s = (e >> 8) & 0x1FFFFu;
        if (s < N_NODES) reg[off[e & (NPB - 1)] + (int)(e >> 25)] = s;
        e = wv.z; s = (e >> 8) & 0x1FFFFu;
        if (s < N_NODES) reg[off[e & (NPB - 1)] + (int)(e >> 25)] = s;
        e = wv.w; s = (e >> 8) & 0x1FFFFu;
        if (s < N_NODES) reg[off[e & (NPB - 1)] + (int)(e >> 25)] = s;
    }
}

// ---- matmul: wave = 64 rows x 4 cols, x in LDS (pad 129), W uniform loads ----
__global__ __launch_bounds__(256) void k_mm1(const float* __restrict__ x,
                                             const float* __restrict__ W1,
                                             const float* __restrict__ dinv,
                                             __half* __restrict__ h1h) {
    __shared__ float sX[MROWS][D_IN + 1];   // 33 KB
    int t = threadIdx.x;
    int r0 = blockIdx.x * MROWS;
    for (int i = t; i < MROWS * (D_IN / 4); i += 256) {
        int row = i >> 5, c4 = i & 31;
        int grow = r0 + row;
        float4 v = (grow < N_NODES) ? ((const float4*)x)[(size_t)grow * 32 + c4]
                                    : make_float4(0.f, 0.f, 0.f, 0.f);
        sX[row][c4 * 4 + 0] = v.x; sX[row][c4 * 4 + 1] = v.y;
        sX[row][c4 * 4 + 2] = v.z; sX[row][c4 * 4 + 3] = v.w;
    }
    __syncthreads();
    int lane = t & 63;
    int c0 = __builtin_amdgcn_readfirstlane((t >> 6) * 4);
    float a0 = 0.f, a1 = 0.f, a2 = 0.f, a3 = 0.f;
#pragma unroll 4
    for (int d = 0; d < D_IN; ++d) {
        float xv = sX[lane][d];
        a0 = fmaf(xv, W1[d * 16 + c0 + 0], a0);
        a1 = fmaf(xv, W1[d * 16 + c0 + 1], a1);
        a2 = fmaf(xv, W1[d * 16 + c0 + 2], a2);
        a3 = fmaf(xv, W1[d * 16 + c0 + 3], a3);
    }
    int grow = r0 + lane;
    if (grow < N_NODES) {
        float di = dinv[grow];
        __half2* o = (__half2*)(h1h + (size_t)grow * H1 + c0);
        o[0] = __floats2half2_rn(a0 * di, a1 * di);
        o[1] = __floats2half2_rn(a2 * di, a3 * di);
    }
}

// ---- layer-1 agg: 8 lanes/node, lane-parallel eop + shfl, half2 gathers ----
__global__ __launch_bounds__(256) void k_agg1(const unsigned int* __restrict__ eop,
                                              const int* __restrict__ nstart,
                                              const int* __restrict__ ndeg,
                                              const __half* __restrict__ h1h,
                                              const float* __restrict__ dinv,
                                              const float* __restrict__ b1,
                                              const float* __restrict__ W2,
                                              float2* __restrict__ h2f) {
    int t = threadIdx.x;
    int g = t >> 3, l = t & 7;               // 32 groups of 8 lanes
    int base = (t & 63) & ~7;                // wave-relative group base lane
    int node = blockIdx.x * 32 + g;          // 3125*32 == N exactly
    int e0 = nstart[node], deg = ndeg[node];
    const __half2* H = (const __half2*)h1h;  // row = 8 half2
    float a0 = 0.f, a1 = 0.f;
    int nfull = deg & ~7;
    int j = e0;
    for (; j < e0 + nfull; j += 8) {         // 8 edges/group per batch
        int s = (int)eop[j + l];             // coalesced 8-wide per group
#pragma unroll
        for (int k = 0; k < 8; ++k) {
            int sk = __shfl(s, base + k);    // broadcast within group
            float2 f = __half22float2(H[sk * 8 + l]);
            a0 += f.x; a1 += f.y;
        }
    }
    int r = e0 + deg - j;                    // 0..7 tail
    if (r) {
        int s = (l < r) ? (int)eop[j + l] : -1;
#pragma unroll
        for (int k = 0; k < 8; ++k) {
            int sk = __shfl(s, base + k);
            int su = (sk >= 0) ? sk : 0;
            float m = (sk >= 0) ? 1.f : 0.f;
            float2 f = __half22float2(H[su * 8 + l]);
            a0 = fmaf(f.x, m, a0); a1 = fmaf(f.y, m, a1);
        }
    }
    float di = dinv[node];
    float2 self = __half22float2(H[node * 8 + l]);   // + self-loop
    float s0 = a0 + self.x, s1 = a1 + self.y;
    float2 bb = ((const float2*)b1)[l];              // b1[2l], b1[2l+1]
    float h0 = fmaxf(fmaf(di, s0, bb.x), 0.f);
    float h1v = fmaxf(fmaf(di, s1, bb.y), 0.f);
    float4 wv = ((const float4*)W2)[l];              // W2 rows 2l, 2l+1
    float p0 = h0 * wv.x + h1v * wv.z;
    float p1 = h0 * wv.y + h1v * wv.w;
#pragma unroll
    for (int off = 1; off < 8; off <<= 1) {
        p0 += __shfl_xor(p0, off);
        p1 += __shfl_xor(p1, off);
    }
    if (l == 0) h2f[node] = make_float2(p0 * di, p1 * di);
}

// ---- layer-2 agg: 4 lanes/node + b2 + log_softmax ----
__global__ __launch_bounds__(256) void k_agg2(const unsigned int* __restrict__ eop,
                                              const int* __restrict__ nstart,
                                              const int* __restrict__ ndeg,
                                              const float2* __restrict__ h2f,
                                              const float* __restrict__ dinv,
                                              const float* __restrict__ b2,
                                              float* __restrict__ out) {
    int tg = blockIdx.x * 256 + threadIdx.x;
    int node = tg >> 2, l = tg & 3;
    if (node >= N_NODES) return;
    int e0 = nstart[node], e1 = e0 + ndeg[node];
    float ax = 0.f, ay = 0.f;
    for (int j = e0 + l; j < e1; j += 4) {
        float2 m = h2f[eop[j]];
        ax += m.x; ay += m.y;
    }
    ax += __shfl_xor(ax, 1); ay += __shfl_xor(ay, 1);
    ax += __shfl_xor(ax, 2); ay += __shfl_xor(ay, 2);
    if (l == 0) {
        float di = dinv[node];
        float2 self = h2f[node];
        float a0 = fmaf(di, ax + self.x, b2[0]);
        float a1 = fmaf(di, ay + self.y, b2[1]);
        float m  = fmaxf(a0, a1);
        float lg = logf(expf(a0 - m) + expf(a1 - m));
        out[2 * node]     = a0 - m - lg;
        out[2 * node + 1] = a1 - m - lg;
    }
}

extern "C" void kernel_launch(void* const* d_in, const int* in_sizes, int n_in,
                              void* d_out, int out_size, void* d_ws, size_t ws_size,
                              hipStream_t stream) {
    const float* x  = (const float*)d_in[0];
    const int*   ei = (const int*)d_in[1];
    const float* W1 = (const float*)d_in[2];
    const float* b1 = (const float*)d_in[3];
    const float* W2 = (const float*)d_in[4];
    const float* b2 = (const float*)d_in[5];
    float* out = (float*)d_out;

    // workspace carve (~25.6 MB); eop base offset 5220352 B = 64B-aligned
    int*          cursor = (int*)d_ws;                       // 512
    int*          nstart = cursor + 512;                     // N (pad 100352)
    int*          ndeg   = nstart + 100352;                  // N (pad 100352)
    float*        dinv   = (float*)(ndeg + 100352);          // N (pad 100352)
    __half*       h1h    = (__half*)(dinv + 100352);         // N*16 halves, 3.2 MB
    float2*       h2f    = (float2*)(h1h + (size_t)100352 * H1);  // N float2
    unsigned int* eop    = (unsigned int*)(h2f + 100352);    // NB*CAP = 20.4 MB

    hipMemsetAsync(cursor, 0, 512 * sizeof(int), stream);    // capture-safe
    k_partition<<<PBLK, 512, 0, stream>>>(ei, cursor, eop);
    k_build    <<<NB,   512, 0, stream>>>(cursor, eop, nstart, ndeg, dinv);
    k_mm1      <<<(N_NODES + MROWS - 1) / MROWS, 256, 0, stream>>>(x, W1, dinv, h1h);
    k_agg1     <<<N_NODES / 32, 256, 0, stream>>>(eop, nstart, ndeg, h1h, dinv, b1, W2, h2f);
    k_agg2     <<<(N_NODES * 4 + 255) / 256, 256, 0, stream>>>(eop, nstart, ndeg, h2f, dinv, b2, out);
}

// Round 4
// 203.967 us; speedup vs baseline: 3.4967x; 1.0121x over previous
//
#include <hip/hip_runtime.h>
#include <hip/hip_fp16.h>
#include <math.h>

#define N_NODES 100000
#define N_EDGES 3200000
#define D_IN    128
#define H1      16

#define PSH     8                      // packing shift: (src<<8 | dloc), dloc < 256
#define NPB     200                    // nodes per bucket (non-pow2; magic div)
#define NB      500                    // 500*200 == N exactly; ~2 blocks/CU balanced
#define CAP     9936                   // region capacity (x16; mean fill ~9264 +5.5sigma)
#define PBLK    512
#define CHUNK   6250                   // N_EDGES / PBLK exact
#define ELS_CAP 13760                  // >= 6250 + 500*15 = 13750, multiple of 16
#define NLINES  (ELS_CAP / 16)         // 860
#define MROWS   64

// bucket of node d: b = floor(d/200) via magic: (d*671089)>>27  (exact, d<1.86M)
__device__ __forceinline__ unsigned bkt(int d) {
    return (unsigned)(((unsigned long long)(unsigned)d * 671089ull) >> 27);
}

// eop: NB regions of CAP uints (region base 64B-aligned).
// k_partition: packed (src<<8 | dloc) runs, run per (block,bucket) padded to
// 16-edge (64B) multiples with 0xFFFFFFFF sentinels; block bucket-sorts its
// chunk in LDS, writes coalesced full 64B lines.
// k_build: ONE LDS-atomic pass (node-degree rank stashed in bits 25..31),
// atomic-free compaction to plain src grouped (CSR) by dst node.
// k_agg1: 8 lanes/node, lane-parallel eop loads + shfl broadcast, half2
// gathers, dual accumulator pairs for ILP.

// ---- partition: rank -> wave-scan -> LDS bucket-sort -> coalesced writeout ----
__global__ __launch_bounds__(512) void k_partition(const int* __restrict__ ei,
                                                   int* __restrict__ cursor,
                                                   unsigned int* __restrict__ eop) {
    __shared__ int h[512];                       // per-bucket counts (pad to 512)
    __shared__ int loff[512];                    // exclusive local run offsets
    __shared__ int resv[NB];                     // global region offsets
    __shared__ int wsum[8], wpre[8];             // cross-wave scan
    __shared__ unsigned short owner[NLINES];     // line -> bucket
    __shared__ unsigned char rank8[CHUNK];       // per-edge rank in its run (<255)
    __shared__ unsigned int els[ELS_CAP];        // 55 KB staging
    int t = threadIdx.x;
    h[t] = 0;
    __syncthreads();
    int c0 = blockIdx.x * CHUNK;
    const int2* s2 = (const int2*)(ei + c0);
    const int2* d2 = (const int2*)(ei + N_EDGES + c0);
    for (int i = t; i < CHUNK / 2; i += 512) {   // int2 loads: count + rank
        int2 dd = d2[i];
        rank8[2 * i]     = (unsigned char)atomicAdd(&h[bkt(dd.x)], 1);
        rank8[2 * i + 1] = (unsigned char)atomicAdd(&h[bkt(dd.y)], 1);
    }
    __syncthreads();
    int cp = (h[t] + 15) & ~15;                  // run padded to 64B multiple
    int lane = t & 63, w = t >> 6;
    int v = cp;                                  // wave-level inclusive scan
#pragma unroll
    for (int o = 1; o < 64; o <<= 1) {
        int u = __shfl_up(v, o);
        if (lane >= o) v += u;
    }
    if (lane == 63) wsum[w] = v;
    __syncthreads();
    if (t < 8) {
        int s = wsum[t];
#pragma unroll
        for (int o = 1; o < 8; o <<= 1) {
            int u = __shfl_up(s, o);
            if (t >= o) s += u;
        }
        wpre[t] = s;                             // inclusive wave prefix
    }
    __syncthreads();
    int inc = v + ((w > 0) ? wpre[w - 1] : 0);   // inclusive over 512
    int totalpad = wpre[7];                      // <= ELS_CAP by construction
    int ex = inc - cp;                           // exclusive
    loff[t] = ex;
    if (t < NB && cp) {
        resv[t] = atomicAdd(&cursor[t], cp);     // stays 16-aligned
        int l0 = ex >> 4;
        for (int k = 0; k < (cp >> 4); ++k) owner[l0 + k] = (unsigned short)t;
    }
    for (int i = t; i < totalpad; i += 512) els[i] = 0xFFFFFFFFu;   // sentinels
    __syncthreads();
    for (int i = t; i < CHUNK / 2; i += 512) {   // LDS bucket-sort scatter
        int2 ss = s2[i];
        int2 dd = d2[i];                         // L2-hot re-read
        unsigned bx = bkt(dd.x), by = bkt(dd.y);
        els[loff[bx] + (int)rank8[2 * i]] =
            ((unsigned)ss.x << PSH) | (unsigned)(dd.x - (int)(bx * NPB));
        els[loff[by] + (int)rank8[2 * i + 1]] =
            ((unsigned)ss.y << PSH) | (unsigned)(dd.y - (int)(by * NPB));
    }
    __syncthreads();
    for (int i = t; i < totalpad; i += 512) {    // coalesced: full 64B lines
        int b   = owner[i >> 4];
        int pos = resv[b] + (i - loff[b]);
        if (pos < CAP)                           // statistically impossible guard
            eop[(size_t)b * CAP + pos] = els[i];
    }
}

// ---- build: uint4 stage, single count+rank atomic pass, atomic-free compaction ----
__global__ __launch_bounds__(512) void k_build(const int* __restrict__ cursor,
                                               unsigned int* __restrict__ eop,
                                               int* __restrict__ nstart,
                                               int* __restrict__ ndeg,
                                               float* __restrict__ dinv) {
    __shared__ unsigned int els[CAP];   // 39.7 KB
    __shared__ int cnt[256];
    __shared__ int off[256];
    __shared__ int wsum[4], wpre[4];
    int t = threadIdx.x, b = blockIdx.x;
    if (t < 256) cnt[t] = 0;
    __syncthreads();
    int n = cursor[b]; if (n > CAP) n = CAP;     // padded fill; multiple of 16
    unsigned int* reg = eop + (size_t)b * CAP;
    for (int i4 = t; i4 < (n >> 2); i4 += 512) { // stage + count + rank, one pass
        uint4 wv = ((const uint4*)reg)[i4];
        unsigned int e0 = wv.x, e1 = wv.y, e2 = wv.z, e3 = wv.w;
        int r;
        if ((int)e0 >= 0) { r = atomicAdd(&cnt[e0 & 0xFF], 1); e0 |= (unsigned)r << 25; }
        if ((int)e1 >= 0) { r = atomicAdd(&cnt[e1 & 0xFF], 1); e1 |= (unsigned)r << 25; }
        if ((int)e2 >= 0) { r = atomicAdd(&cnt[e2 & 0xFF], 1); e2 |= (unsigned)r << 25; }
        if ((int)e3 >= 0) { r = atomicAdd(&cnt[e3 & 0xFF], 1); e3 |= (unsigned)r << 25; }
        ((uint4*)els)[i4] = make_uint4(e0, e1, e2, e3);
    }
    __syncthreads();
    int lane = t & 63, w = t >> 6;
    int v = 0;
    if (t < 256) {                               // 4-wave inclusive scan
        v = cnt[t];
#pragma unroll
        for (int o = 1; o < 64; o <<= 1) {
            int u = __shfl_up(v, o);
            if (lane >= o) v += u;
        }
        if (lane == 63) wsum[w] = v;
    }
    __syncthreads();
    if (t < 4) {
        int s = wsum[t];
#pragma unroll
        for (int o = 1; o < 4; o <<= 1) {
            int u = __shfl_up(s, o);
            if (t >= o) s += u;
        }
        wpre[t] = s;
    }
    __syncthreads();
    if (t < 256) {
        int val = cnt[t];
        int ex = (v + ((w > 0) ? wpre[w - 1] : 0)) - val;   // exclusive
        off[t] = ex;
        if (t < NPB) {
            int node = b * NPB + t;              // NB*NPB == N exactly
            nstart[node] = b * CAP + ex;
            ndeg[node]   = val;
            dinv[node]   = rsqrtf((float)(val + 1));   // +1 self-loop
        }
    }
    __syncthreads();
    for (int i4 = t; i4 < (n >> 2); i4 += 512) { // rank-addressed compact CSR
        uint4 wv = ((const uint4*)els)[i4];
        unsigned int e; unsigned s;
        e = wv.x; s = (e >> PSH) & 0x1FFFFu;
        if (s < N_NODES) reg[off[e & 0xFF] + (int)(e >> 25)] = s;
        e = wv.y; s = (e >> PSH) & 0x1FFFFu;
        if (s < N_NODES) reg[off[e & 0xFF] + (int)(e >> 25)] = s;
        e = wv.z; s = (e >> PSH) & 0x1FFFFu;
        if (s < N_NODES) reg[off[e & 0xFF] + (int)(e >> 25)] = s;
        e = wv.w; s = (e >> PSH) & 0x1FFFFu;
        if (s < N_NODES) reg[off[e & 0xFF] + (int)(e >> 25)] = s;
    }
}

// ---- matmul: wave = 64 rows x 4 cols, x in LDS (pad 129), W uniform loads ----
__global__ __launch_bounds__(256) void k_mm1(const float* __restrict__ x,
                                             const float* __restrict__ W1,
                                             const float* __restrict__ dinv,
                                             __half* __restrict__ h1h) {
    __shared__ float sX[MROWS][D_IN + 1];   // 33 KB
    int t = threadIdx.x;
    int r0 = blockIdx.x * MROWS;
    for (int i = t; i < MROWS * (D_IN / 4); i += 256) {
        int row = i >> 5, c4 = i & 31;
        int grow = r0 + row;
        float4 v = (grow < N_NODES) ? ((const float4*)x)[(size_t)grow * 32 + c4]
                                    : make_float4(0.f, 0.f, 0.f, 0.f);
        sX[row][c4 * 4 + 0] = v.x; sX[row][c4 * 4 + 1] = v.y;
        sX[row][c4 * 4 + 2] = v.z; sX[row][c4 * 4 + 3] = v.w;
    }
    __syncthreads();
    int lane = t & 63;
    int c0 = __builtin_amdgcn_readfirstlane((t >> 6) * 4);
    float a0 = 0.f, a1 = 0.f, a2 = 0.f, a3 = 0.f;
#pragma unroll 4
    for (int d = 0; d < D_IN; ++d) {
        float xv = sX[lane][d];
        a0 = fmaf(xv, W1[d * 16 + c0 + 0], a0);
        a1 = fmaf(xv, W1[d * 16 + c0 + 1], a1);
        a2 = fmaf(xv, W1[d * 16 + c0 + 2], a2);
        a3 = fmaf(xv, W1[d * 16 + c0 + 3], a3);
    }
    int grow = r0 + lane;
    if (grow < N_NODES) {
        float di = dinv[grow];
        __half2* o = (__half2*)(h1h + (size_t)grow * H1 + c0);
        o[0] = __floats2half2_rn(a0 * di, a1 * di);
        o[1] = __floats2half2_rn(a2 * di, a3 * di);
    }
}

// ---- layer-1 agg: 8 lanes/node, lane-parallel eop + shfl, half2 gathers,
//      dual accumulator pairs ----
__global__ __launch_bounds__(256) void k_agg1(const unsigned int* __restrict__ eop,
                                              const int* __restrict__ nstart,
                                              const int* __restrict__ ndeg,
                                              const __half* __restrict__ h1h,
                                              const float* __restrict__ dinv,
                                              const float* __restrict__ b1,
                                              const float* __restrict__ W2,
                                              float2* __restrict__ h2f) {
    int t = threadIdx.x;
    int g = t >> 3, l = t & 7;               // 32 groups of 8 lanes
    int base = (t & 63) & ~7;                // wave-relative group base lane
    int node = blockIdx.x * 32 + g;          // 3125*32 == N exactly
    int e0 = nstart[node], deg = ndeg[node];
    const __half2* H = (const __half2*)h1h;  // row = 8 half2
    float a0 = 0.f, a1 = 0.f, c0 = 0.f, c1 = 0.f;
    int nfull = deg & ~7;
    int j = e0;
    for (; j < e0 + nfull; j += 8) {         // 8 edges/group per batch
        int s = (int)eop[j + l];             // coalesced 8-wide per group
#pragma unroll
        for (int k = 0; k < 8; k += 2) {     // dual accum: halve dep chain
            int sk0 = __shfl(s, base + k);
            int sk1 = __shfl(s, base + k + 1);
            float2 f0 = __half22float2(H[sk0 * 8 + l]);
            float2 f1 = __half22float2(H[sk1 * 8 + l]);
            a0 += f0.x; a1 += f0.y;
            c0 += f1.x; c1 += f1.y;
        }
    }
    int r = e0 + deg - j;                    // 0..7 tail
    if (r) {
        int s = (l < r) ? (int)eop[j + l] : -1;
#pragma unroll
        for (int k = 0; k < 8; ++k) {
            int sk = __shfl(s, base + k);
            int su = (sk >= 0) ? sk : 0;
            float m = (sk >= 0) ? 1.f : 0.f;
            float2 f = __half22float2(H[su * 8 + l]);
            a0 = fmaf(f.x, m, a0); a1 = fmaf(f.y, m, a1);
        }
    }
    float di = dinv[node];
    float2 self = __half22float2(H[node * 8 + l]);   // + self-loop
    float s0 = (a0 + c0) + self.x, s1 = (a1 + c1) + self.y;
    float2 bb = ((const float2*)b1)[l];              // b1[2l], b1[2l+1]
    float h0 = fmaxf(fmaf(di, s0, bb.x), 0.f);
    float h1v = fmaxf(fmaf(di, s1, bb.y), 0.f);
    float4 wv = ((const float4*)W2)[l];              // W2 rows 2l, 2l+1
    float p0 = h0 * wv.x + h1v * wv.z;
    float p1 = h0 * wv.y + h1v * wv.w;
#pragma unroll
    for (int off = 1; off < 8; off <<= 1) {
        p0 += __shfl_xor(p0, off);
        p1 += __shfl_xor(p1, off);
    }
    if (l == 0) h2f[node] = make_float2(p0 * di, p1 * di);
}

// ---- layer-2 agg: 4 lanes/node + b2 + log_softmax ----
__global__ __launch_bounds__(256) void k_agg2(const unsigned int* __restrict__ eop,
                                              const int* __restrict__ nstart,
                                              const int* __restrict__ ndeg,
                                              const float2* __restrict__ h2f,
                                              const float* __restrict__ dinv,
                                              const float* __restrict__ b2,
                                              float* __restrict__ out) {
    int tg = blockIdx.x * 256 + threadIdx.x;
    int node = tg >> 2, l = tg & 3;
    if (node >= N_NODES) return;
    int e0 = nstart[node], e1 = e0 + ndeg[node];
    float ax = 0.f, ay = 0.f;
    for (int j = e0 + l; j < e1; j += 4) {
        float2 m = h2f[eop[j]];
        ax += m.x; ay += m.y;
    }
    ax += __shfl_xor(ax, 1); ay += __shfl_xor(ay, 1);
    ax += __shfl_xor(ax, 2); ay += __shfl_xor(ay, 2);
    if (l == 0) {
        float di = dinv[node];
        float2 self = h2f[node];
        float a0 = fmaf(di, ax + self.x, b2[0]);
        float a1 = fmaf(di, ay + self.y, b2[1]);
        float m  = fmaxf(a0, a1);
        float lg = logf(expf(a0 - m) + expf(a1 - m));
        out[2 * node]     = a0 - m - lg;
        out[2 * node + 1] = a1 - m - lg;
    }
}

extern "C" void kernel_launch(void* const* d_in, const int* in_sizes, int n_in,
                              void* d_out, int out_size, void* d_ws, size_t ws_size,
                              hipStream_t stream) {
    const float* x  = (const float*)d_in[0];
    const int*   ei = (const int*)d_in[1];
    const float* W1 = (const float*)d_in[2];
    const float* b1 = (const float*)d_in[3];
    const float* W2 = (const float*)d_in[4];
    const float* b2 = (const float*)d_in[5];
    float* out = (float*)d_out;

    // workspace carve (~25.1 MB); eop base offset 5220352 B = 64B-aligned
    int*          cursor = (int*)d_ws;                       // 512
    int*          nstart = cursor + 512;                     // N (pad 100352)
    int*          ndeg   = nstart + 100352;                  // N (pad 100352)
    float*        dinv   = (float*)(ndeg + 100352);          // N (pad 100352)
    __half*       h1h    = (__half*)(dinv + 100352);         // N*16 halves, 3.2 MB
    float2*       h2f    = (float2*)(h1h + (size_t)100352 * H1);  // N float2
    unsigned int* eop    = (unsigned int*)(h2f + 100352);    // NB*CAP = 19.9 MB

    hipMemsetAsync(cursor, 0, 512 * sizeof(int), stream);    // capture-safe
    k_partition<<<PBLK, 512, 0, stream>>>(ei, cursor, eop);
    k_build    <<<NB,   512, 0, stream>>>(cursor, eop, nstart, ndeg, dinv);
    k_mm1      <<<(N_NODES + MROWS - 1) / MROWS, 256, 0, stream>>>(x, W1, dinv, h1h);
    k_agg1     <<<N_NODES / 32, 256, 0, stream>>>(eop, nstart, ndeg, h1h, dinv, b1, W2, h2f);
    k_agg2     <<<(N_NODES * 4 + 255) / 256, 256, 0, stream>>>(eop, nstart, ndeg, h2f, dinv, b2, out);
}